// Round 1
// baseline (15.805 us; speedup 1.0000x reference)
//
#include <hip/hip_runtime.h>

// Problem constants (B,C,H,W = 2,512,64,64; 8 heads x 64 dim)
namespace {
constexpr int kC      = 512;
constexpr int kHW     = 4096;              // 64*64
constexpr int kB      = 2;
constexpr int kTotal  = kB * kC * kHW;     // 4,194,304 floats
constexpr int kTotal4 = kTotal / 4;        // 1,048,576 float4
}

// wps[o] = sum_c w_proj[o,c]  (the output projection applied to a
// channel-constant input collapses to its row-sum).
__global__ void wps_sum_kernel(const float* __restrict__ w_proj,
                               float* __restrict__ wps) {
    const int o    = blockIdx.x;       // 512 blocks
    const int lane = threadIdx.x;      // 64 threads = 1 wave
    float s = 0.f;
    #pragma unroll
    for (int c = lane; c < kC; c += 64) s += w_proj[o * kC + c];
    #pragma unroll
    for (int off = 32; off > 0; off >>= 1) s += __shfl_down(s, off);
    if (lane == 0) wps[o] = s;
}

// out[b,o,y,x] = x[b,o,y,x]
//              + wps[o] * 4096 * b_qkv[1024 + (x&7)*64 + (y&7)*8 + (x>>3)]
//              + b_proj[o]
// Derivation: einsum('bnqk,bnvd') = rowsum(softmax)=1 outer colsum(v);
// colsum(v) = HW*b_qkv_v since spatial-sum of InstanceNorm output == 0;
// faithful permute/reshape makes the broadcast pattern above, independent
// of channel, so w_proj enters only via its row-sums.
__global__ void fused_out_kernel(const float* __restrict__ x,
                                 const float* __restrict__ b_qkv,
                                 const float* __restrict__ b_proj,
                                 const float* __restrict__ wps,
                                 float* __restrict__ out) {
    const int i4 = blockIdx.x * blockDim.x + threadIdx.x;
    if (i4 >= kTotal4) return;
    const int x0 = (i4 & 15) << 2;          // x coord of 1st of 4 (mult of 4)
    const int y  = (i4 >> 4) & 63;
    const int o  = (i4 >> 10) & 511;        // channel (b = i4>>19, unused)

    const float4 xv = reinterpret_cast<const float4*>(x)[i4];
    const float w4096 = wps[o] * 4096.f;
    const float bp    = b_proj[o];

    // b_qkv index: 1024 + (x&7)*64 + (y&7)*8 + (x>>3); x0..x0+3 share x>>3.
    const int base = 1024 + ((y & 7) << 3) + (x0 >> 3);
    const int n0   = x0 & 7;                // 0 or 4

    float4 ov;
    ov.x = fmaf(w4096, b_qkv[base + (n0 + 0) * 64], bp) + xv.x;
    ov.y = fmaf(w4096, b_qkv[base + (n0 + 1) * 64], bp) + xv.y;
    ov.z = fmaf(w4096, b_qkv[base + (n0 + 2) * 64], bp) + xv.z;
    ov.w = fmaf(w4096, b_qkv[base + (n0 + 3) * 64], bp) + xv.w;
    reinterpret_cast<float4*>(out)[i4] = ov;
}

extern "C" void kernel_launch(void* const* d_in, const int* in_sizes, int n_in,
                              void* d_out, int out_size, void* d_ws, size_t ws_size,
                              hipStream_t stream) {
    const float* x      = (const float*)d_in[0];
    // d_in[1] = w_qkv: unused — it only touches the output through
    // sum_spatial(instancenorm(x)) == 0.
    const float* b_qkv  = (const float*)d_in[2];
    const float* w_proj = (const float*)d_in[3];
    const float* b_proj = (const float*)d_in[4];
    float* out = (float*)d_out;
    float* wps = (float*)d_ws;              // 512 floats of scratch

    wps_sum_kernel<<<kC, 64, 0, stream>>>(w_proj, wps);
    fused_out_kernel<<<kTotal4 / 256, 256, 0, stream>>>(x, b_qkv, b_proj, wps, out);
}

// Round 2
// 11.401 us; speedup vs baseline: 1.3863x; 1.3863x over previous
//
#include <hip/hip_runtime.h>

// Problem constants (B,C,H,W = 2,512,64,64; 8 heads x 64 dim)
namespace {
constexpr int kC       = 512;
constexpr int kHW      = 4096;             // 64*64
constexpr int kB       = 2;
constexpr int kBlocks  = kB * kC;          // one block per (batch, channel): 1024
}

// out[b,o,y,x] = x[b,o,y,x]
//              + rowsum(w_proj[o,:]) * 4096 * b_qkv[1024 + (x&7)*64 + (y&7)*8 + (x>>3)]
//              + b_proj[o]
//
// Derivation: einsum('bnqk,bnvd') = rowsum(softmax)=1 (outer) colsum(v);
// colsum(v) = HW*b_qkv_v because the spatial sum of InstanceNorm output is
// identically 0 (so w_qkv and x's statistics drop out). The faithful
// permute(0,2,3,1).reshape makes the added term channel-independent, so
// w_proj enters only via its row-sums.
__global__ __launch_bounds__(256) void fused_attn_collapse_kernel(
        const float* __restrict__ x,
        const float* __restrict__ b_qkv,
        const float* __restrict__ b_proj,
        const float* __restrict__ w_proj,
        float* __restrict__ out) {
    const int bo   = blockIdx.x;           // (batch*512 + channel)
    const int o    = bo & (kC - 1);
    const int tid  = threadIdx.x;          // 0..255
    const int lane = tid & 63;
    const int wid  = tid >> 6;

    // Issue the x loads immediately — they cover the reduction latency.
    const float4* __restrict__ xin = reinterpret_cast<const float4*>(x) + bo * (kHW / 4);
    float4 xv[4];
    #pragma unroll
    for (int r = 0; r < 4; ++r) xv[r] = xin[tid + r * 256];

    // Block-cooperative row-sum of w_proj[o, :] (512 floats, 2 per thread).
    const float* __restrict__ wrow = w_proj + o * kC;
    float s = wrow[tid] + wrow[tid + 256];
    #pragma unroll
    for (int off = 32; off > 0; off >>= 1) s += __shfl_down(s, off);
    __shared__ float sp[4];
    if (lane == 0) sp[wid] = s;
    __syncthreads();
    const float w4096 = (sp[0] + sp[1] + sp[2] + sp[3]) * 4096.f;
    const float bp    = b_proj[o];

    float4* __restrict__ oout = reinterpret_cast<float4*>(out) + bo * (kHW / 4);
    #pragma unroll
    for (int r = 0; r < 4; ++r) {
        const int j  = tid + r * 256;      // float4 index within the 64x64 plane
        const int x0 = (j & 15) << 2;      // x coord of 1st of 4 (multiple of 4)
        const int y  = (j >> 4) & 63;
        // b_qkv index: 1024 + (x&7)*64 + (y&7)*8 + (x>>3); x0..x0+3 share x>>3.
        const int base = 1024 + ((y & 7) << 3) + (x0 >> 3);
        const int n0   = x0 & 7;           // 0 or 4
        float4 ov;
        ov.x = fmaf(w4096, b_qkv[base + (n0 + 0) * 64], bp) + xv[r].x;
        ov.y = fmaf(w4096, b_qkv[base + (n0 + 1) * 64], bp) + xv[r].y;
        ov.z = fmaf(w4096, b_qkv[base + (n0 + 2) * 64], bp) + xv[r].z;
        ov.w = fmaf(w4096, b_qkv[base + (n0 + 3) * 64], bp) + xv[r].w;
        oout[j] = ov;
    }
}

extern "C" void kernel_launch(void* const* d_in, const int* in_sizes, int n_in,
                              void* d_out, int out_size, void* d_ws, size_t ws_size,
                              hipStream_t stream) {
    const float* x      = (const float*)d_in[0];
    // d_in[1] = w_qkv: unused — it reaches the output only through
    // sum_spatial(instancenorm(x)) == 0.
    const float* b_qkv  = (const float*)d_in[2];
    const float* w_proj = (const float*)d_in[3];
    const float* b_proj = (const float*)d_in[4];
    float* out = (float*)d_out;

    fused_attn_collapse_kernel<<<kBlocks, 256, 0, stream>>>(x, b_qkv, b_proj, w_proj, out);
}

// Round 3
// 11.317 us; speedup vs baseline: 1.3967x; 1.0074x over previous
//
#include <hip/hip_runtime.h>

// Problem constants (B,C,H,W = 2,512,64,64; 8 heads x 64 dim)
namespace {
constexpr int kC      = 512;
constexpr int kHW     = 4096;              // 64*64
constexpr int kB      = 2;
constexpr int kBlocks = kB * kC;           // one block per (batch, channel): 1024
}

// out[b,o,y,x] = x[b,o,y,x]
//              + rowsum(w_proj[o,:]) * 4096 * b_qkv[1024 + (x&7)*64 + (y&7)*8 + (x>>3)]
//              + b_proj[o]
//
// Derivation: einsum('bnqk,bnvd') = rowsum(softmax)=1 (outer) colsum(v);
// colsum(v) = HW*b_qkv_v because the spatial sum of InstanceNorm output is
// identically 0 (so w_qkv and x's statistics drop out). The faithful
// permute(0,2,3,1).reshape makes the added term channel-independent, so
// w_proj enters only via its row-sums.
//
// Structure notes:
// - per-WAVE w_proj row-sum (shfl_xor tree): no LDS, no __syncthreads —
//   each wave streams independently.
// - for j = tid + r*256, (x&15) and (y&7) are invariant in r, so the
//   b_qkv additive term is computed ONCE per thread and reused 4x.
__global__ __launch_bounds__(256) void fused_attn_collapse_kernel(
        const float* __restrict__ x,
        const float* __restrict__ b_qkv,
        const float* __restrict__ b_proj,
        const float* __restrict__ w_proj,
        float* __restrict__ out) {
    const int bo   = blockIdx.x;           // batch*512 + channel
    const int o    = bo & (kC - 1);
    const int tid  = threadIdx.x;          // 0..255
    const int lane = tid & 63;

    // Issue the x loads immediately — they cover everything else.
    const float4* __restrict__ xin = reinterpret_cast<const float4*>(x) + bo * (kHW / 4);
    float4 xv[4];
    #pragma unroll
    for (int r = 0; r < 4; ++r) xv[r] = xin[tid + r * 256];

    // b_qkv term pattern (invariant across the 4 r-iterations):
    //   x0 = (j&15)<<2, y&7 = (j>>4)&7  — both depend only on tid.
    const int x0   = (tid & 15) << 2;
    const int base = 1024 + (((tid >> 4) & 7) << 3) + (x0 >> 3);
    const int n0   = x0 & 7;               // 0 or 4
    const float bq0 = b_qkv[base + (n0 + 0) * 64];
    const float bq1 = b_qkv[base + (n0 + 1) * 64];
    const float bq2 = b_qkv[base + (n0 + 2) * 64];
    const float bq3 = b_qkv[base + (n0 + 3) * 64];

    // Per-wave row-sum of w_proj[o,:]: lane reads 8 consecutive floats
    // (two float4), local sum, then 6-step shfl_xor tree -> all lanes hold s.
    const float4* __restrict__ wrow4 = reinterpret_cast<const float4*>(w_proj + o * kC);
    const float4 wa = wrow4[lane * 2 + 0];
    const float4 wb = wrow4[lane * 2 + 1];
    float s = (wa.x + wa.y + wa.z + wa.w) + (wb.x + wb.y + wb.z + wb.w);
    #pragma unroll
    for (int off = 32; off > 0; off >>= 1) s += __shfl_xor(s, off);

    const float w4096 = s * 4096.f;
    const float bp    = b_proj[o];
    float4 term;
    term.x = fmaf(w4096, bq0, bp);
    term.y = fmaf(w4096, bq1, bp);
    term.z = fmaf(w4096, bq2, bp);
    term.w = fmaf(w4096, bq3, bp);

    float4* __restrict__ oout = reinterpret_cast<float4*>(out) + bo * (kHW / 4);
    #pragma unroll
    for (int r = 0; r < 4; ++r) {
        float4 ov;
        ov.x = xv[r].x + term.x;
        ov.y = xv[r].y + term.y;
        ov.z = xv[r].z + term.z;
        ov.w = xv[r].w + term.w;
        oout[tid + r * 256] = ov;
    }
}

extern "C" void kernel_launch(void* const* d_in, const int* in_sizes, int n_in,
                              void* d_out, int out_size, void* d_ws, size_t ws_size,
                              hipStream_t stream) {
    const float* x      = (const float*)d_in[0];
    // d_in[1] = w_qkv: unused — it reaches the output only through
    // sum_spatial(instancenorm(x)) == 0.
    const float* b_qkv  = (const float*)d_in[2];
    const float* w_proj = (const float*)d_in[3];
    const float* b_proj = (const float*)d_in[4];
    float* out = (float*)d_out;

    fused_attn_collapse_kernel<<<kBlocks, 256, 0, stream>>>(x, b_qkv, b_proj, w_proj, out);
}